// Round 1
// baseline (589.015 us; speedup 1.0000x reference)
//
#include <hip/hip_runtime.h>
#include <hip/hip_bf16.h>

// Problem: B=16384, H=2048
//   bdnf = sigmoid(x @ W^T + b)
//   xs   = x * pm
//   fi   = xs * (xs @ M^T) * (0.5/H)
//   out  = xs + bdnf * fi
// Identity: xs @ M^T = x @ (M * pm[col])^T  -> both GEMMs share A = bf16(x).

#define M_DIM 16384
#define H_DIM 2048
#define BM 128
#define BN 128
#define BK 64
#define NTHREADS 512

typedef __attribute__((ext_vector_type(8))) short short8;
typedef __attribute__((ext_vector_type(4))) float floatx4;

#define GPTR(p) ((const __attribute__((address_space(1))) void*)(p))
#define LPTR(p) ((__attribute__((address_space(3))) void*)(p))

__device__ __forceinline__ unsigned short f2bf(float f) {
    __hip_bfloat16 h = __float2bfloat16(f);
    return *reinterpret_cast<unsigned short*>(&h);
}

// ---- pre-pass 1: xbf = bf16(x) -------------------------------------------
__global__ void cvt_x_kernel(const float* __restrict__ x,
                             unsigned short* __restrict__ xbf, long n) {
    long stride = (long)gridDim.x * blockDim.x * 4;
    for (long j = ((long)blockIdx.x * blockDim.x + threadIdx.x) * 4; j < n; j += stride) {
        float4 v = *reinterpret_cast<const float4*>(x + j);
        ushort4 o;
        o.x = f2bf(v.x); o.y = f2bf(v.y); o.z = f2bf(v.z); o.w = f2bf(v.w);
        *reinterpret_cast<ushort4*>(xbf + j) = o;
    }
}

// ---- pre-pass 2: Wbf = bf16(W); Mbf[j,k] = bf16(M[j,k]*pm[k]) ------------
__global__ void cvt_wm_kernel(const float* __restrict__ W,
                              const float* __restrict__ Mk,
                              const float* __restrict__ pm,
                              unsigned short* __restrict__ Wbf,
                              unsigned short* __restrict__ Mbf, long n) {
    long stride = (long)gridDim.x * blockDim.x * 4;
    for (long j = ((long)blockIdx.x * blockDim.x + threadIdx.x) * 4; j < n; j += stride) {
        float4 w = *reinterpret_cast<const float4*>(W + j);
        float4 m = *reinterpret_cast<const float4*>(Mk + j);
        float4 p = *reinterpret_cast<const float4*>(pm + (j & (H_DIM - 1)));
        ushort4 ow, om;
        ow.x = f2bf(w.x); ow.y = f2bf(w.y); ow.z = f2bf(w.z); ow.w = f2bf(w.w);
        om.x = f2bf(m.x * p.x); om.y = f2bf(m.y * p.y);
        om.z = f2bf(m.z * p.z); om.w = f2bf(m.w * p.w);
        *reinterpret_cast<ushort4*>(Wbf + j) = ow;
        *reinterpret_cast<ushort4*>(Mbf + j) = om;
    }
}

// ---- fused dual-GEMM + epilogue ------------------------------------------
// m97 structure: 128x128 tile, BK=64, global_load_lds w=16, single-buffer.
// 8 waves (512 thr): wave w -> sub-tile (wr=w>>1: 32 rows, wc=w&1: 64 cols).
// Per wave: acc1/acc2 [2][4] fragments of 16x16.
__global__ __launch_bounds__(NTHREADS)
void fused_gemm_kernel(const unsigned short* __restrict__ xbf,
                       const unsigned short* __restrict__ Wbf,
                       const unsigned short* __restrict__ Mbf,
                       const float* __restrict__ x,
                       const float* __restrict__ bias,
                       const float* __restrict__ pm,
                       float* __restrict__ out) {
    __shared__ __align__(16) unsigned short sA[BM * BK];
    __shared__ __align__(16) unsigned short sW[BN * BK];
    __shared__ __align__(16) unsigned short sM[BN * BK];

    const int t    = threadIdx.x;
    const int brow = blockIdx.y * BM;
    const int bcol = blockIdx.x * BN;

    // staging map: thread t covers row=t>>3 (and +64), 8 bf16 at col (t&7)*8
    const int srow = t >> 3;
    const int scol = (t & 7) * 8;

    const int w    = t >> 6;
    const int lane = t & 63;
    const int wr   = w >> 1;       // 0..3 : 32-row strip
    const int wc   = w & 1;        // 0..1 : 64-col strip
    const int lrow = lane & 15;
    const int lk8  = (lane >> 4) * 8;

    floatx4 acc1[2][4], acc2[2][4];
#pragma unroll
    for (int m = 0; m < 2; ++m)
#pragma unroll
        for (int n = 0; n < 4; ++n) {
            acc1[m][n] = (floatx4){0.f, 0.f, 0.f, 0.f};
            acc2[m][n] = (floatx4){0.f, 0.f, 0.f, 0.f};
        }

    const unsigned short* gA0 = xbf + (size_t)(brow + srow) * H_DIM + scol;
    const unsigned short* gW0 = Wbf + (size_t)(bcol + srow) * H_DIM + scol;
    const unsigned short* gM0 = Mbf + (size_t)(bcol + srow) * H_DIM + scol;

    for (int kt = 0; kt < H_DIM; kt += BK) {
        __builtin_amdgcn_global_load_lds(GPTR(gA0 + kt), LPTR(&sA[srow * BK + scol]), 16, 0, 0);
        __builtin_amdgcn_global_load_lds(GPTR(gA0 + kt + (size_t)64 * H_DIM),
                                         LPTR(&sA[(srow + 64) * BK + scol]), 16, 0, 0);
        __builtin_amdgcn_global_load_lds(GPTR(gW0 + kt), LPTR(&sW[srow * BK + scol]), 16, 0, 0);
        __builtin_amdgcn_global_load_lds(GPTR(gW0 + kt + (size_t)64 * H_DIM),
                                         LPTR(&sW[(srow + 64) * BK + scol]), 16, 0, 0);
        __builtin_amdgcn_global_load_lds(GPTR(gM0 + kt), LPTR(&sM[srow * BK + scol]), 16, 0, 0);
        __builtin_amdgcn_global_load_lds(GPTR(gM0 + kt + (size_t)64 * H_DIM),
                                         LPTR(&sM[(srow + 64) * BK + scol]), 16, 0, 0);
        __syncthreads();

#pragma unroll
        for (int ks = 0; ks < 2; ++ks) {
            const int ko = ks * 32 + lk8;
            short8 aA[2], bW[4], bM[4];
#pragma unroll
            for (int m = 0; m < 2; ++m)
                aA[m] = *reinterpret_cast<const short8*>(&sA[(wr * 32 + m * 16 + lrow) * BK + ko]);
#pragma unroll
            for (int n = 0; n < 4; ++n) {
                bW[n] = *reinterpret_cast<const short8*>(&sW[(wc * 64 + n * 16 + lrow) * BK + ko]);
                bM[n] = *reinterpret_cast<const short8*>(&sM[(wc * 64 + n * 16 + lrow) * BK + ko]);
            }
#pragma unroll
            for (int m = 0; m < 2; ++m)
#pragma unroll
                for (int n = 0; n < 4; ++n) {
                    acc1[m][n] = __builtin_amdgcn_mfma_f32_16x16x32_bf16(aA[m], bW[n], acc1[m][n], 0, 0, 0);
                    acc2[m][n] = __builtin_amdgcn_mfma_f32_16x16x32_bf16(aA[m], bM[n], acc2[m][n], 0, 0, 0);
                }
        }
        __syncthreads();
    }

    // epilogue: out = xs + sigmoid(S1+b) * xs * S2 * (0.5/H), xs = x*pm (fp32)
    const float c = 0.5f / (float)H_DIM;
#pragma unroll
    for (int n = 0; n < 4; ++n) {
        const int gcol = bcol + wc * 64 + n * 16 + lrow;
        const float bj  = bias[gcol];
        const float pmj = pm[gcol];
#pragma unroll
        for (int m = 0; m < 2; ++m) {
            floatx4 a1 = acc1[m][n];
            floatx4 a2 = acc2[m][n];
            const int growb = brow + wr * 32 + m * 16 + (lane >> 4) * 4;
#pragma unroll
            for (int r = 0; r < 4; ++r) {
                const size_t idx = (size_t)(growb + r) * H_DIM + gcol;
                const float xs  = x[idx] * pmj;
                const float s1  = a1[r] + bj;
                const float sig = 1.0f / (1.0f + __expf(-s1));
                out[idx] = xs + sig * (xs * a2[r] * c);
            }
        }
    }
}

extern "C" void kernel_launch(void* const* d_in, const int* in_sizes, int n_in,
                              void* d_out, int out_size, void* d_ws, size_t ws_size,
                              hipStream_t stream) {
    const float* x   = (const float*)d_in[0];
    const float* W   = (const float*)d_in[1];
    const float* b   = (const float*)d_in[2];
    const float* pm  = (const float*)d_in[3];
    const float* Mk  = (const float*)d_in[4];
    float* out = (float*)d_out;

    const long n_x = (long)M_DIM * H_DIM;      // 33.5M
    const long n_w = (long)H_DIM * H_DIM;      // 4.2M

    // workspace layout (bytes): xbf [0, 67.1MB) | Wbf | Mbf  -> 80 MB total
    unsigned short* xbf = (unsigned short*)d_ws;
    unsigned short* Wbf = xbf + n_x;
    unsigned short* Mbf = Wbf + n_w;

    cvt_x_kernel<<<4096, 256, 0, stream>>>(x, xbf, n_x);
    cvt_wm_kernel<<<2048, 256, 0, stream>>>(W, Mk, pm, Wbf, Mbf, n_w);

    dim3 grid(H_DIM / BN, M_DIM / BM);   // (16, 128)
    fused_gemm_kernel<<<grid, NTHREADS, 0, stream>>>(xbf, Wbf, Mbf, x, b, pm, out);
}

// Round 2
// 416.575 us; speedup vs baseline: 1.4139x; 1.4139x over previous
//
#include <hip/hip_runtime.h>
#include <hip/hip_bf16.h>

// Problem: B=16384, H=2048
//   bdnf = sigmoid(x @ W^T + b)
//   xs   = x * pm
//   fi   = xs * (xs @ M^T) * (0.5/H)
//   out  = xs + bdnf * fi
// Identity: xs @ M^T = x @ (M * pm[col])^T  -> both GEMMs share A = bf16(x).
//
// R2: T2 XOR-swizzle on all three LDS tiles. global_load_lds writes linearly
// (wave-uniform base + lane*16), so the swizzle is applied by permuting the
// GLOBAL source chunk (chunk ^= row&7) and applying the same XOR on ds_read
// addresses (rule #21: both-sides involution).

#define M_DIM 16384
#define H_DIM 2048
#define BM 128
#define BN 128
#define BK 64
#define NTHREADS 512

typedef __attribute__((ext_vector_type(8))) short short8;
typedef __attribute__((ext_vector_type(4))) float floatx4;

#define GPTR(p) ((const __attribute__((address_space(1))) void*)(p))
#define LPTR(p) ((__attribute__((address_space(3))) void*)(p))

__device__ __forceinline__ unsigned short f2bf(float f) {
    __hip_bfloat16 h = __float2bfloat16(f);
    return *reinterpret_cast<unsigned short*>(&h);
}

// ---- pre-pass 1: xbf = bf16(x) -------------------------------------------
__global__ void cvt_x_kernel(const float* __restrict__ x,
                             unsigned short* __restrict__ xbf, long n) {
    long stride = (long)gridDim.x * blockDim.x * 4;
    for (long j = ((long)blockIdx.x * blockDim.x + threadIdx.x) * 4; j < n; j += stride) {
        float4 v = *reinterpret_cast<const float4*>(x + j);
        ushort4 o;
        o.x = f2bf(v.x); o.y = f2bf(v.y); o.z = f2bf(v.z); o.w = f2bf(v.w);
        *reinterpret_cast<ushort4*>(xbf + j) = o;
    }
}

// ---- pre-pass 2: Wbf = bf16(W); Mbf[j,k] = bf16(M[j,k]*pm[k]) ------------
__global__ void cvt_wm_kernel(const float* __restrict__ W,
                              const float* __restrict__ Mk,
                              const float* __restrict__ pm,
                              unsigned short* __restrict__ Wbf,
                              unsigned short* __restrict__ Mbf, long n) {
    long stride = (long)gridDim.x * blockDim.x * 4;
    for (long j = ((long)blockIdx.x * blockDim.x + threadIdx.x) * 4; j < n; j += stride) {
        float4 w = *reinterpret_cast<const float4*>(W + j);
        float4 m = *reinterpret_cast<const float4*>(Mk + j);
        float4 p = *reinterpret_cast<const float4*>(pm + (j & (H_DIM - 1)));
        ushort4 ow, om;
        ow.x = f2bf(w.x); ow.y = f2bf(w.y); ow.z = f2bf(w.z); ow.w = f2bf(w.w);
        om.x = f2bf(m.x * p.x); om.y = f2bf(m.y * p.y);
        om.z = f2bf(m.z * p.z); om.w = f2bf(m.w * p.w);
        *reinterpret_cast<ushort4*>(Wbf + j) = ow;
        *reinterpret_cast<ushort4*>(Mbf + j) = om;
    }
}

// swizzled ds_read: fragment at (row, ko) of a [rows][BK] bf16 tile.
// chunk (16B unit) index is XOR'd with row&7 -> lanes 0..15 spread over 8 slots.
__device__ __forceinline__ short8 lds_frag(const unsigned short* s, int row, int ko) {
    const int sw = (((ko >> 3) ^ (row & 7)) << 3);
    return *reinterpret_cast<const short8*>(&s[row * BK + sw]);
}

// ---- fused dual-GEMM + epilogue ------------------------------------------
__global__ __launch_bounds__(NTHREADS)
void fused_gemm_kernel(const unsigned short* __restrict__ xbf,
                       const unsigned short* __restrict__ Wbf,
                       const unsigned short* __restrict__ Mbf,
                       const float* __restrict__ x,
                       const float* __restrict__ bias,
                       const float* __restrict__ pm,
                       float* __restrict__ out) {
    __shared__ __align__(16) unsigned short sA[BM * BK];
    __shared__ __align__(16) unsigned short sW[BN * BK];
    __shared__ __align__(16) unsigned short sM[BN * BK];

    const int t    = threadIdx.x;
    const int brow = blockIdx.y * BM;
    const int bcol = blockIdx.x * BN;

    // staging map: thread t covers row srow=t>>3 (and +64).
    // LDS dest stays LINEAR (t*16 bytes); the global source chunk is
    // pre-swizzled: chunk_g = (t&7) ^ (srow&7).
    const int srow    = t >> 3;
    const int chunk   = t & 7;
    const int scol_l  = chunk * 8;                        // linear LDS col
    const int scol_g  = (chunk ^ (srow & 7)) * 8;         // swizzled global col

    const int w    = t >> 6;
    const int lane = t & 63;
    const int wr   = w >> 1;       // 0..3 : 32-row strip
    const int wc   = w & 1;        // 0..1 : 64-col strip
    const int lrow = lane & 15;
    const int lk8  = (lane >> 4) * 8;

    floatx4 acc1[2][4], acc2[2][4];
#pragma unroll
    for (int m = 0; m < 2; ++m)
#pragma unroll
        for (int n = 0; n < 4; ++n) {
            acc1[m][n] = (floatx4){0.f, 0.f, 0.f, 0.f};
            acc2[m][n] = (floatx4){0.f, 0.f, 0.f, 0.f};
        }

    const unsigned short* gA0 = xbf + (size_t)(brow + srow) * H_DIM + scol_g;
    const unsigned short* gW0 = Wbf + (size_t)(bcol + srow) * H_DIM + scol_g;
    const unsigned short* gM0 = Mbf + (size_t)(bcol + srow) * H_DIM + scol_g;

    for (int kt = 0; kt < H_DIM; kt += BK) {
        __builtin_amdgcn_global_load_lds(GPTR(gA0 + kt), LPTR(&sA[srow * BK + scol_l]), 16, 0, 0);
        __builtin_amdgcn_global_load_lds(GPTR(gA0 + kt + (size_t)64 * H_DIM),
                                         LPTR(&sA[(srow + 64) * BK + scol_l]), 16, 0, 0);
        __builtin_amdgcn_global_load_lds(GPTR(gW0 + kt), LPTR(&sW[srow * BK + scol_l]), 16, 0, 0);
        __builtin_amdgcn_global_load_lds(GPTR(gW0 + kt + (size_t)64 * H_DIM),
                                         LPTR(&sW[(srow + 64) * BK + scol_l]), 16, 0, 0);
        __builtin_amdgcn_global_load_lds(GPTR(gM0 + kt), LPTR(&sM[srow * BK + scol_l]), 16, 0, 0);
        __builtin_amdgcn_global_load_lds(GPTR(gM0 + kt + (size_t)64 * H_DIM),
                                         LPTR(&sM[(srow + 64) * BK + scol_l]), 16, 0, 0);
        __syncthreads();

#pragma unroll
        for (int ks = 0; ks < 2; ++ks) {
            const int ko = ks * 32 + lk8;
            short8 aA[2], bW[4], bM[4];
#pragma unroll
            for (int m = 0; m < 2; ++m)
                aA[m] = lds_frag(sA, wr * 32 + m * 16 + lrow, ko);
#pragma unroll
            for (int n = 0; n < 4; ++n) {
                bW[n] = lds_frag(sW, wc * 64 + n * 16 + lrow, ko);
                bM[n] = lds_frag(sM, wc * 64 + n * 16 + lrow, ko);
            }
#pragma unroll
            for (int m = 0; m < 2; ++m)
#pragma unroll
                for (int n = 0; n < 4; ++n) {
                    acc1[m][n] = __builtin_amdgcn_mfma_f32_16x16x32_bf16(aA[m], bW[n], acc1[m][n], 0, 0, 0);
                    acc2[m][n] = __builtin_amdgcn_mfma_f32_16x16x32_bf16(aA[m], bM[n], acc2[m][n], 0, 0, 0);
                }
        }
        __syncthreads();
    }

    // epilogue: out = xs + sigmoid(S1+b) * xs * S2 * (0.5/H), xs = x*pm (fp32)
    const float c = 0.5f / (float)H_DIM;
#pragma unroll
    for (int n = 0; n < 4; ++n) {
        const int gcol = bcol + wc * 64 + n * 16 + lrow;
        const float bj  = bias[gcol];
        const float pmj = pm[gcol];
#pragma unroll
        for (int m = 0; m < 2; ++m) {
            floatx4 a1 = acc1[m][n];
            floatx4 a2 = acc2[m][n];
            const int growb = brow + wr * 32 + m * 16 + (lane >> 4) * 4;
#pragma unroll
            for (int r = 0; r < 4; ++r) {
                const size_t idx = (size_t)(growb + r) * H_DIM + gcol;
                const float xs  = x[idx] * pmj;
                const float s1  = a1[r] + bj;
                const float sig = 1.0f / (1.0f + __expf(-s1));
                out[idx] = xs + sig * (xs * a2[r] * c);
            }
        }
    }
}

extern "C" void kernel_launch(void* const* d_in, const int* in_sizes, int n_in,
                              void* d_out, int out_size, void* d_ws, size_t ws_size,
                              hipStream_t stream) {
    const float* x   = (const float*)d_in[0];
    const float* W   = (const float*)d_in[1];
    const float* b   = (const float*)d_in[2];
    const float* pm  = (const float*)d_in[3];
    const float* Mk  = (const float*)d_in[4];
    float* out = (float*)d_out;

    const long n_x = (long)M_DIM * H_DIM;      // 33.5M
    const long n_w = (long)H_DIM * H_DIM;      // 4.2M

    // workspace layout: xbf | Wbf | Mbf  -> ~84 MB total
    unsigned short* xbf = (unsigned short*)d_ws;
    unsigned short* Wbf = xbf + n_x;
    unsigned short* Mbf = Wbf + n_w;

    cvt_x_kernel<<<4096, 256, 0, stream>>>(x, xbf, n_x);
    cvt_wm_kernel<<<2048, 256, 0, stream>>>(W, Mk, pm, Wbf, Mbf, n_w);

    dim3 grid(H_DIM / BN, M_DIM / BM);   // (16, 128)
    fused_gemm_kernel<<<grid, NTHREADS, 0, stream>>>(xbf, Wbf, Mbf, x, b, pm, out);
}

// Round 3
// 325.509 us; speedup vs baseline: 1.8095x; 1.2798x over previous
//
#include <hip/hip_runtime.h>
#include <hip/hip_bf16.h>

// Problem: B=16384, H=2048
//   bdnf = sigmoid(x @ W^T + b)
//   xs   = x * pm
//   fi   = xs * (xs @ M^T) * (0.5/H)
//   out  = xs + bdnf * fi
// Identity: xs @ M^T = x @ (M * pm[col])^T  -> both GEMMs share A = bf16(x).
//
// R3: 8-phase/counted-vmcnt schedule (T3+T4+T5) on top of R2's T2 swizzle.
// BM=256 BN=128 BK=64, 8 waves (4Mx2N), per-wave 64x64 dual output.
// Per K-tile 4 phases: (W,ks0)(W,ks1)(M,ks0)(M,ks1), 16 MFMA each; A frags
// register-resident across the tile. Prefetch t+1: A @ph0, W+M @ph1.
// Waits: vmcnt(8) end-ph1 (drains prev tile's M), vmcnt(2) end-ph3
// (drains next tile's A+W, M stays in flight). Raw s_barrier everywhere.

#define M_DIM 16384
#define H_DIM 2048
#define BM 256
#define BN 128
#define BK 64
#define NTHREADS 512

typedef __attribute__((ext_vector_type(8))) short short8;
typedef __attribute__((ext_vector_type(4))) float floatx4;

#define GPTR(p) ((const __attribute__((address_space(1))) void*)(p))
#define LPTR(p) ((__attribute__((address_space(3))) void*)(p))

__device__ __forceinline__ unsigned short f2bf(float f) {
    __hip_bfloat16 h = __float2bfloat16(f);
    return *reinterpret_cast<unsigned short*>(&h);
}

// ---- pre-pass 1: xbf = bf16(x) -------------------------------------------
__global__ void cvt_x_kernel(const float* __restrict__ x,
                             unsigned short* __restrict__ xbf, long n) {
    long stride = (long)gridDim.x * blockDim.x * 4;
    for (long j = ((long)blockIdx.x * blockDim.x + threadIdx.x) * 4; j < n; j += stride) {
        float4 v = *reinterpret_cast<const float4*>(x + j);
        ushort4 o;
        o.x = f2bf(v.x); o.y = f2bf(v.y); o.z = f2bf(v.z); o.w = f2bf(v.w);
        *reinterpret_cast<ushort4*>(xbf + j) = o;
    }
}

// ---- pre-pass 2: Wbf = bf16(W); Mbf[j,k] = bf16(M[j,k]*pm[k]) ------------
__global__ void cvt_wm_kernel(const float* __restrict__ W,
                              const float* __restrict__ Mk,
                              const float* __restrict__ pm,
                              unsigned short* __restrict__ Wbf,
                              unsigned short* __restrict__ Mbf, long n) {
    long stride = (long)gridDim.x * blockDim.x * 4;
    for (long j = ((long)blockIdx.x * blockDim.x + threadIdx.x) * 4; j < n; j += stride) {
        float4 w = *reinterpret_cast<const float4*>(W + j);
        float4 m = *reinterpret_cast<const float4*>(Mk + j);
        float4 p = *reinterpret_cast<const float4*>(pm + (j & (H_DIM - 1)));
        ushort4 ow, om;
        ow.x = f2bf(w.x); ow.y = f2bf(w.y); ow.z = f2bf(w.z); ow.w = f2bf(w.w);
        om.x = f2bf(m.x * p.x); om.y = f2bf(m.y * p.y);
        om.z = f2bf(m.z * p.z); om.w = f2bf(m.w * p.w);
        *reinterpret_cast<ushort4*>(Wbf + j) = ow;
        *reinterpret_cast<ushort4*>(Mbf + j) = om;
    }
}

// swizzled ds_read: fragment at (row, ko) of a [rows][BK] bf16 tile.
__device__ __forceinline__ short8 lds_frag(const unsigned short* s, int row, int ko) {
    const int sw = (((ko >> 3) ^ (row & 7)) << 3);
    return *reinterpret_cast<const short8*>(&s[row * BK + sw]);
}

#define GLDS(src, dst) __builtin_amdgcn_global_load_lds(GPTR(src), LPTR(dst), 16, 0, 0)

#define STAGE_A(b, kt) do { \
    GLDS(gA0 + (kt),                      &sA[b][(srow      ) * BK + scol_l]); \
    GLDS(gA0 + (kt) + (size_t)64 *H_DIM,  &sA[b][(srow +  64) * BK + scol_l]); \
    GLDS(gA0 + (kt) + (size_t)128*H_DIM,  &sA[b][(srow + 128) * BK + scol_l]); \
    GLDS(gA0 + (kt) + (size_t)192*H_DIM,  &sA[b][(srow + 192) * BK + scol_l]); } while (0)

#define STAGE_W(b, kt) do { \
    GLDS(gW0 + (kt),                      &sW[b][(srow     ) * BK + scol_l]); \
    GLDS(gW0 + (kt) + (size_t)64 *H_DIM,  &sW[b][(srow + 64) * BK + scol_l]); } while (0)

#define STAGE_M(b, kt) do { \
    GLDS(gM0 + (kt),                      &sM[b][(srow     ) * BK + scol_l]); \
    GLDS(gM0 + (kt) + (size_t)64 *H_DIM,  &sM[b][(srow + 64) * BK + scol_l]); } while (0)

#define BAR() __builtin_amdgcn_s_barrier()
#define LGK0() do { asm volatile("s_waitcnt lgkmcnt(0)" ::: "memory"); \
                    __builtin_amdgcn_sched_barrier(0); } while (0)

// ph0: A ks0 + W ks0 -> acc1 ; stage next-tile A
#define PH0(ct, nt_, ktn) do { \
    _Pragma("unroll") for (int m = 0; m < 4; ++m) aA0[m] = lds_frag(sA[ct], arow + m * 16, lk8); \
    _Pragma("unroll") for (int n = 0; n < 4; ++n) bB[n]  = lds_frag(sW[ct], brw + n * 16, lk8); \
    STAGE_A(nt_, ktn); \
    BAR(); LGK0(); \
    __builtin_amdgcn_s_setprio(1); \
    _Pragma("unroll") for (int m = 0; m < 4; ++m) \
    _Pragma("unroll") for (int n = 0; n < 4; ++n) \
        acc1[m][n] = __builtin_amdgcn_mfma_f32_16x16x32_bf16(aA0[m], bB[n], acc1[m][n], 0, 0, 0); \
    __builtin_amdgcn_s_setprio(0); \
    BAR(); } while (0)

// ph1: A ks1 + W ks1 -> acc1 ; stage next-tile W,M ; vmcnt(8) drains cur M
#define PH1(ct, nt_, ktn) do { \
    _Pragma("unroll") for (int m = 0; m < 4; ++m) aA1[m] = lds_frag(sA[ct], arow + m * 16, 32 + lk8); \
    _Pragma("unroll") for (int n = 0; n < 4; ++n) bB[n]  = lds_frag(sW[ct], brw + n * 16, 32 + lk8); \
    STAGE_W(nt_, ktn); STAGE_M(nt_, ktn); \
    BAR(); LGK0(); \
    __builtin_amdgcn_s_setprio(1); \
    _Pragma("unroll") for (int m = 0; m < 4; ++m) \
    _Pragma("unroll") for (int n = 0; n < 4; ++n) \
        acc1[m][n] = __builtin_amdgcn_mfma_f32_16x16x32_bf16(aA1[m], bB[n], acc1[m][n], 0, 0, 0); \
    __builtin_amdgcn_s_setprio(0); \
    asm volatile("s_waitcnt vmcnt(8)" ::: "memory"); \
    BAR(); } while (0)

// ph2: M ks0 -> acc2 (A from regs)
#define PH2(ct) do { \
    _Pragma("unroll") for (int n = 0; n < 4; ++n) bB[n] = lds_frag(sM[ct], brw + n * 16, lk8); \
    BAR(); LGK0(); \
    __builtin_amdgcn_s_setprio(1); \
    _Pragma("unroll") for (int m = 0; m < 4; ++m) \
    _Pragma("unroll") for (int n = 0; n < 4; ++n) \
        acc2[m][n] = __builtin_amdgcn_mfma_f32_16x16x32_bf16(aA0[m], bB[n], acc2[m][n], 0, 0, 0); \
    __builtin_amdgcn_s_setprio(0); \
    BAR(); } while (0)

// ph3: M ks1 -> acc2 ; vmcnt(2) drains next tile's A+W (M stays in flight)
#define PH3(ct) do { \
    _Pragma("unroll") for (int n = 0; n < 4; ++n) bB[n] = lds_frag(sM[ct], brw + n * 16, 32 + lk8); \
    BAR(); LGK0(); \
    __builtin_amdgcn_s_setprio(1); \
    _Pragma("unroll") for (int m = 0; m < 4; ++m) \
    _Pragma("unroll") for (int n = 0; n < 4; ++n) \
        acc2[m][n] = __builtin_amdgcn_mfma_f32_16x16x32_bf16(aA1[m], bB[n], acc2[m][n], 0, 0, 0); \
    __builtin_amdgcn_s_setprio(0); \
    asm volatile("s_waitcnt vmcnt(2)" ::: "memory"); \
    BAR(); } while (0)

// ---- fused dual-GEMM + epilogue ------------------------------------------
__global__ __launch_bounds__(NTHREADS, 2)
void fused_gemm_kernel(const unsigned short* __restrict__ xbf,
                       const unsigned short* __restrict__ Wbf,
                       const unsigned short* __restrict__ Mbf,
                       const float* __restrict__ x,
                       const float* __restrict__ bias,
                       const float* __restrict__ pm,
                       float* __restrict__ out) {
    __shared__ __align__(16) unsigned short sA[2][BM * BK];  // 2 x 32 KB
    __shared__ __align__(16) unsigned short sW[2][BN * BK];  // 2 x 16 KB
    __shared__ __align__(16) unsigned short sM[2][BN * BK];  // 2 x 16 KB

    const int t    = threadIdx.x;
    const int brow = blockIdx.y * BM;
    const int bcol = blockIdx.x * BN;

    // staging map: thread t covers rows srow (+64,+128,+192 for A), linear
    // LDS dest (t*16B within each 64-row pass), global col pre-swizzled.
    const int srow   = t >> 3;
    const int chunk  = t & 7;
    const int scol_l = chunk * 8;
    const int scol_g = (chunk ^ (srow & 7)) * 8;

    const int w    = t >> 6;
    const int lane = t & 63;
    const int wr   = w >> 1;             // 0..3 : 64-row strip
    const int wc   = w & 1;              // 0..1 : 64-col strip
    const int lrow = lane & 15;
    const int lk8  = (lane >> 4) * 8;
    const int arow = wr * 64 + lrow;     // A-frag base row (+m*16)
    const int brw  = wc * 64 + lrow;     // B-frag base row (+n*16)

    floatx4 acc1[4][4], acc2[4][4];
#pragma unroll
    for (int m = 0; m < 4; ++m)
#pragma unroll
        for (int n = 0; n < 4; ++n) {
            acc1[m][n] = (floatx4){0.f, 0.f, 0.f, 0.f};
            acc2[m][n] = (floatx4){0.f, 0.f, 0.f, 0.f};
        }

    const unsigned short* gA0 = xbf + (size_t)(brow + srow) * H_DIM + scol_g;
    const unsigned short* gW0 = Wbf + (size_t)(bcol + srow) * H_DIM + scol_g;
    const unsigned short* gM0 = Mbf + (size_t)(bcol + srow) * H_DIM + scol_g;

    // prologue: stage tile 0, wait A+W (M may still fly)
    STAGE_A(0, 0); STAGE_W(0, 0); STAGE_M(0, 0);
    asm volatile("s_waitcnt vmcnt(2)" ::: "memory");
    BAR();

    short8 aA0[4], aA1[4], bB[4];

#pragma unroll 1
    for (int i = 0; i < H_DIM / (2 * BK); ++i) {
        const int kn0 = i * 2 * BK + BK;                     // prefetch for buf1 tile
        const int kn1 = (i * 2 * BK + 2 * BK) & (H_DIM - 1); // prefetch for next buf0 (wraps)
        PH0(0, 1, kn0); PH1(0, 1, kn0); PH2(0); PH3(0);
        PH0(1, 0, kn1); PH1(1, 0, kn1); PH2(1); PH3(1);
    }

    // epilogue: out = xs + sigmoid(S1+b) * xs * S2 * (0.5/H), xs = x*pm (fp32)
    const float c = 0.5f / (float)H_DIM;
#pragma unroll
    for (int n = 0; n < 4; ++n) {
        const int gcol = bcol + wc * 64 + n * 16 + lrow;
        const float bj  = bias[gcol];
        const float pmj = pm[gcol];
#pragma unroll
        for (int m = 0; m < 4; ++m) {
            floatx4 a1 = acc1[m][n];
            floatx4 a2 = acc2[m][n];
            const int growb = brow + wr * 64 + m * 16 + (lane >> 4) * 4;
#pragma unroll
            for (int r = 0; r < 4; ++r) {
                const size_t idx = (size_t)(growb + r) * H_DIM + gcol;
                const float xs  = x[idx] * pmj;
                const float s1  = a1[r] + bj;
                const float sig = 1.0f / (1.0f + __expf(-s1));
                out[idx] = xs + sig * (xs * a2[r] * c);
            }
        }
    }
}

extern "C" void kernel_launch(void* const* d_in, const int* in_sizes, int n_in,
                              void* d_out, int out_size, void* d_ws, size_t ws_size,
                              hipStream_t stream) {
    const float* x   = (const float*)d_in[0];
    const float* W   = (const float*)d_in[1];
    const float* b   = (const float*)d_in[2];
    const float* pm  = (const float*)d_in[3];
    const float* Mk  = (const float*)d_in[4];
    float* out = (float*)d_out;

    const long n_x = (long)M_DIM * H_DIM;      // 33.5M
    const long n_w = (long)H_DIM * H_DIM;      // 4.2M

    // workspace layout: xbf | Wbf | Mbf  -> ~84 MB total
    unsigned short* xbf = (unsigned short*)d_ws;
    unsigned short* Wbf = xbf + n_x;
    unsigned short* Mbf = Wbf + n_w;

    cvt_x_kernel<<<4096, 256, 0, stream>>>(x, xbf, n_x);
    cvt_wm_kernel<<<2048, 256, 0, stream>>>(W, Mk, pm, Wbf, Mbf, n_w);

    dim3 grid(H_DIM / BN, M_DIM / BM);   // (16, 64)
    fused_gemm_kernel<<<grid, NTHREADS, 0, stream>>>(xbf, Wbf, Mbf, x, b, pm, out);
}